// Round 10
// baseline (622.287 us; speedup 1.0000x reference)
//
#include <hip/hip_runtime.h>

// VectorQuantizer: latents [32,64,64,64] f32, embedding [1024,64] f32.
// Outputs flat in d_out (f32): vq_loss @0, perplexity @1,
// out [32,64,64,64] @2, one_hot [131072,1024] @8388610.
//
// N = 131072 rows, D = 64, K = 1024. Block = 4 waves, 64 rows; wave wq
// handles k-quarter [wq*256, +256) in 32 tiles of 8 codes. Argmin combined
// via LDS ascending-wq strict < (np.argmin first-index tie-break).
//
// Settled design facts (rounds 2-9): x[64] CANNOT be kept in VGPRs at HIP
// level (allocator remats from global or spills pinned values; launch
// bounds / waves_per_eu / asm pins all failed). x therefore lives in LDS
// and is re-read per tile (round 5, 309us). Round-5's limiter: LDS pipe
// = FMA pipe = 109us (16KB LDS read per 4 codes). THIS ROUND: 8-code
// tiles with 4-d chunks -> same live-register footprint as round 5's
// passing loop (32 e + 4 x + 8 acc), but HALF the LDS bytes per FMA
// (55us pipe). x read as 2x ds_read_b64 (XS=66: 8B-aligned, 2-way banks
// = free). e addresses wave-uniform (L1-broadcast/s_load; round 6 proved
// per-lane e pointers are fatal).
//
// ws float layout:
//   ne      [0, 1024)      ||e_k||^2 (numpy pairwise-8 order)
//   counts  [1024, 2048)   uint32 histogram of inds
//   partials[2048, 10240)  per-wave f32 loss partial sums (8192)

#define KEMB 1024
#define DEMB 64
#define XS 66   // LDS x row stride (floats); 264B: 8B-aligned, 2-way banks

__global__ __launch_bounds__(256) void vq_prep(const float* __restrict__ emb,
                                               float* __restrict__ ne,
                                               unsigned int* __restrict__ counts) {
#pragma clang fp contract(off)
    int k = blockIdx.x * 256 + threadIdx.x;
    if (k >= KEMB) return;
    counts[k] = 0u;
    float v[DEMB];
#pragma unroll
    for (int d = 0; d < DEMB; ++d) v[d] = emb[k * DEMB + d];
    // numpy pairwise sum, n=64: 8 strided accumulators then tree combine
    float r[8];
#pragma unroll
    for (int j = 0; j < 8; ++j) r[j] = v[j] * v[j];
#pragma unroll
    for (int i = 8; i < 64; i += 8)
#pragma unroll
        for (int j = 0; j < 8; ++j) r[j] = r[j] + v[i + j] * v[i + j];
    ne[k] = ((r[0] + r[1]) + (r[2] + r[3])) + ((r[4] + r[5]) + (r[6] + r[7]));
}

__global__ __launch_bounds__(256, 6) void vq_main(const float* __restrict__ lat,
                                                  const float* __restrict__ emb,
                                                  const float* __restrict__ ne,
                                                  float* __restrict__ outq,
                                                  float* __restrict__ onehot,
                                                  unsigned int* __restrict__ counts,
                                                  float* __restrict__ partials) {
    __shared__ float xls[64 * XS];        // 16,896 B
    __shared__ float sbest[4][64];
    __shared__ int sbi[4][64];

    const int lane = threadIdx.x & 63;
    const int wq = __builtin_amdgcn_readfirstlane(threadIdx.x >> 6); // 0..3, SGPR
    const int n0 = blockIdx.x * 64;       // first row of this block
    const int bimg = n0 >> 12;            // 4096 rows per image
    const int hw0 = n0 & 4095;

    // Stage x tile: wave wq loads d in [wq*16, wq*16+16) for all 64 rows.
    // Global: for fixed d, 64 lanes read consecutive hw -> 256B coalesced.
    // LDS write banks: (lane*66 + d)%32 = (2*lane + d)%32 -> 2-way, free.
    {
        const float* latp = lat + (size_t)bimg * (DEMB * 4096) + hw0 + lane;
#pragma unroll
        for (int dd = 0; dd < 16; ++dd) {
            int d = (wq << 4) + dd;
            xls[lane * XS + d] = latp[(size_t)d * 4096];
        }
    }
    __syncthreads();

    const float* xl = &xls[lane * XS];    // this lane's row (row = lane)

    // nx = ||x||^2 in numpy pairwise-8 order, no FMA contraction.
    float nx;
    {
#pragma clang fp contract(off)
        float r[8];
#pragma unroll
        for (int j = 0; j < 8; ++j) { float v = xl[j]; r[j] = v * v; }
#pragma unroll
        for (int i = 8; i < 64; i += 8)
#pragma unroll
            for (int j = 0; j < 8; ++j) { float v = xl[i + j]; r[j] = r[j] + v * v; }
        nx = ((r[0] + r[1]) + (r[2] + r[3])) + ((r[4] + r[5]) + (r[6] + r[7]));
    }

    // k-quarter loop: 32 tiles of 8 contiguous codes (2KB of emb per tile,
    // wave-uniform addresses). dot = sequential FMA chain over d per code
    // (= np BLAS micro-kernel order, bit-exact); 8 independent chains.
    // Inner structure: 16 chunks of 4 d -> per chunk: 2 ds_read_b64 for x
    // (free banks) + 8 float4 e-loads (uniform addr -> broadcast) + 32 FMA.
    // Live set/chunk ~= 32 e + 4 x + 8 acc: same footprint that passed in
    // round 5. LDS bytes per FMA HALVED vs round 5.
    // 2 one_hot rows zero-filled per tile (HBM writes overlap VALU).
    float2* ohf2 = (float2*)onehot;
    const float2 z2 = make_float2(0.0f, 0.0f);
    float best = __builtin_inff();
    int bi = 0;
    const int kbase = wq << 8;
    const float* et = emb + (size_t)kbase * DEMB;
    const float* nq = ne + kbase;
    for (int t = 0; t < 32; ++t) {
        float a0 = 0.0f, a1 = 0.0f, a2 = 0.0f, a3 = 0.0f;
        float a4 = 0.0f, a5 = 0.0f, a6 = 0.0f, a7 = 0.0f;
#pragma unroll
        for (int c = 0; c < 16; ++c) {
            // x chunk: d in [4c, 4c+4) via two b64 reads (8B-aligned)
            float2 xA = *(const float2*)(xl + 4 * c);
            float2 xB = *(const float2*)(xl + 4 * c + 2);
#define CODE_FMA(J, AJ)                                                     \
            {                                                               \
                float4 ev = ((const float4*)(et + 64 * (J)))[c];            \
                AJ = __builtin_fmaf(xA.x, ev.x, AJ);                        \
                AJ = __builtin_fmaf(xA.y, ev.y, AJ);                        \
                AJ = __builtin_fmaf(xB.x, ev.z, AJ);                        \
                AJ = __builtin_fmaf(xB.y, ev.w, AJ);                        \
            }
            CODE_FMA(0, a0)
            CODE_FMA(1, a1)
            CODE_FMA(2, a2)
            CODE_FMA(3, a3)
            CODE_FMA(4, a4)
            CODE_FMA(5, a5)
            CODE_FMA(6, a6)
            CODE_FMA(7, a7)
#undef CODE_FMA
        }
        {
#pragma clang fp contract(off)
            const int k0 = kbase + (t << 3);
            float d0 = (nx + nq[t * 8 + 0]) - 2.0f * a0;
            float d1 = (nx + nq[t * 8 + 1]) - 2.0f * a1;
            float d2 = (nx + nq[t * 8 + 2]) - 2.0f * a2;
            float d3 = (nx + nq[t * 8 + 3]) - 2.0f * a3;
            float d4 = (nx + nq[t * 8 + 4]) - 2.0f * a4;
            float d5 = (nx + nq[t * 8 + 5]) - 2.0f * a5;
            float d6 = (nx + nq[t * 8 + 6]) - 2.0f * a6;
            float d7 = (nx + nq[t * 8 + 7]) - 2.0f * a7;
            if (d0 < best) { best = d0; bi = k0 + 0; }
            if (d1 < best) { best = d1; bi = k0 + 1; }
            if (d2 < best) { best = d2; bi = k0 + 2; }
            if (d3 < best) { best = d3; bi = k0 + 3; }
            if (d4 < best) { best = d4; bi = k0 + 4; }
            if (d5 < best) { best = d5; bi = k0 + 5; }
            if (d6 < best) { best = d6; bi = k0 + 6; }
            if (d7 < best) { best = d7; bi = k0 + 7; }
        }
        et += 512;   // 8 codes * 64 floats
        // zero-fill: wave wq covers one_hot chunks [wq*128, +128) of rows
        // (n0+2t) and (n0+2t+1); 32 tiles x 2 rows = all 64 rows.
        float2* zp = ohf2 + (((size_t)(n0 + 2 * t)) << 9) + (wq << 7) + lane;
        zp[0] = z2;
        zp[64] = z2;
        zp[512] = z2;
        zp[576] = z2;
    }

    sbest[wq][lane] = best;
    sbi[wq][lane] = bi;
    __syncthreads();   // also drains vmcnt -> all zero stores complete

    // combine quarters in ascending order, strict < (first-index tie-break)
    float bb = sbest[0][lane];
    int ib = sbi[0][lane];
#pragma unroll
    for (int qq = 1; qq < 4; ++qq) {
        float c = sbest[qq][lane];
        int ci = sbi[qq][lane];
        if (c < bb) { bb = c; ib = ci; }
    }

    if (wq == 0) {
        onehot[(size_t)(n0 + lane) * KEMB + ib] = 1.0f;
        atomicAdd(&counts[ib], 1u);
    }

    // out = lat + (q - lat); loss partial. Wave wq handles d in [wq*16,+16).
    float lsum = 0.0f;
    const size_t obase = (size_t)bimg * (DEMB * 4096) + hw0 + lane;
    {
#pragma clang fp contract(off)
        const float4* eq4 = (const float4*)(emb + (size_t)ib * DEMB + (wq << 4));
#pragma unroll
        for (int c4 = 0; c4 < 4; ++c4) {
            float4 qv = eq4[c4];
            int dbase = (wq << 4) + 4 * c4;
            float xv0 = xl[dbase + 0];
            float xv1 = xl[dbase + 1];
            float xv2 = xl[dbase + 2];
            float xv3 = xl[dbase + 3];
            float f0 = qv.x - xv0, f1 = qv.y - xv1;
            float f2 = qv.z - xv2, f3 = qv.w - xv3;
            outq[obase + (size_t)(dbase + 0) * 4096] = xv0 + f0;
            outq[obase + (size_t)(dbase + 1) * 4096] = xv1 + f1;
            outq[obase + (size_t)(dbase + 2) * 4096] = xv2 + f2;
            outq[obase + (size_t)(dbase + 3) * 4096] = xv3 + f3;
            lsum = lsum + f0 * f0;
            lsum = lsum + f1 * f1;
            lsum = lsum + f2 * f2;
            lsum = lsum + f3 * f3;
        }
    }
#pragma unroll
    for (int off = 32; off > 0; off >>= 1) lsum += __shfl_xor(lsum, off, 64);
    if (lane == 0) partials[blockIdx.x * 4 + wq] = lsum;
}

__global__ __launch_bounds__(1024) void vq_final(const unsigned int* __restrict__ counts,
                                                 const float* __restrict__ partials,
                                                 float* __restrict__ out01) {
    __shared__ float sb[1024];
    int t = threadIdx.x;
    // vq_loss: deterministic tree over 8192 per-wave partials
    float s = 0.0f;
#pragma unroll
    for (int i = 0; i < 8; ++i) s += partials[t + 1024 * i];
    sb[t] = s;
    __syncthreads();
    for (int off = 512; off > 0; off >>= 1) {
        if (t < off) sb[t] = sb[t] + sb[t + off];
        __syncthreads();
    }
    if (t == 0) {
        float m = sb[0] / 8388608.0f;   // mean of (q-lat)^2
        out01[0] = m * 0.25f + m;       // BETA*commitment + embedding
    }
    __syncthreads();
    // perplexity: avg_probs = counts / N (exact), entropy tree, exp.
    float p = (float)counts[t] * (1.0f / 131072.0f);
    sb[t] = p * logf(p + 1e-10f);
    __syncthreads();
    for (int off = 512; off > 0; off >>= 1) {
        if (t < off) sb[t] = sb[t] + sb[t + off];
        __syncthreads();
    }
    if (t == 0) out01[1] = expf(-sb[0]);
}

extern "C" void kernel_launch(void* const* d_in, const int* in_sizes, int n_in,
                              void* d_out, int out_size, void* d_ws, size_t ws_size,
                              hipStream_t stream) {
    const float* lat = (const float*)d_in[0];
    const float* emb = (const float*)d_in[1];
    float* out = (float*)d_out;
    float* ws = (float*)d_ws;

    float* ne = ws;
    unsigned int* counts = (unsigned int*)(ws + 1024);
    float* partials = ws + 2048;

    float* outq = out + 2;
    float* onehot = out + 2 + 8388608;

    vq_prep<<<4, 256, 0, stream>>>(emb, ne, counts);
    vq_main<<<2048, 256, 0, stream>>>(lat, emb, ne, outq, onehot, counts, partials);
    vq_final<<<1, 1024, 0, stream>>>(counts, partials, out);
}

// Round 11
// 317.081 us; speedup vs baseline: 1.9625x; 1.9625x over previous
//
#include <hip/hip_runtime.h>

// VectorQuantizer via MFMA-filter + exact-refine.
// latents [32,64,64,64] f32, embedding [1024,64] f32.
// d_out f32: vq_loss @0, perplexity @1, out @2, one_hot @8388610.
//
// Rounds 2-10 proved the f32-VALU all-pairs scan is compiler-capped at
// ~300us (register working sets >32 get spilled/parked/rematerialized no
// matter what hints are given). This kernel moves the bulk scan to the
// idle MFMA pipe in bf16 with a RIGOROUS conservative threshold, then
// re-checks the few candidates with the reference-exact f32 arithmetic
// (pairwise-8 norms, sequential-FMA dot, contract-off dist, first-index
// tie-break) so the final argmin matches numpy bit-exactly.
//
// Block = 256 thr = 4 waves, 64 rows. Wave wq owns rows [wq*16,+16) x ALL
// 1024 codes: A-frag = 4 VGPR, C = 4 VGPR -> no register pressure.
// Per wave per pass: 64 N-tiles x 2 K-steps = 128 MFMA.
//
// ws layout (f32 slots):
//   ne     [0,1024)            ||e_k||^2 (numpy pairwise-8)
//   ebf    [1024,33792)        E in bf16 pairs (uint32), [1024][32]
//   emax4  [33792,33796)       per-prep-block max|e|
//   counts [33796,34820)       uint32 histogram
//   partials [34820,43012)     per-wave loss partials (8192)

#define KEMB 1024
#define DEMB 64
#define XS 66

typedef __attribute__((ext_vector_type(8))) short bf16x8;
typedef __attribute__((ext_vector_type(4))) float f32x4;

union AU { unsigned int u[4]; bf16x8 v; };

__device__ inline unsigned int f2bf1(float f) {   // RN-even f32->bf16 bits
    unsigned int u = __float_as_uint(f);
    return (u + 0x7FFFu + ((u >> 16) & 1u)) >> 16;
}

__global__ __launch_bounds__(256) void vq_prep(const float* __restrict__ emb,
                                               float* __restrict__ ne,
                                               unsigned int* __restrict__ ebf,
                                               unsigned int* __restrict__ counts,
                                               float* __restrict__ emax4) {
#pragma clang fp contract(off)
    __shared__ float sm[4];
    int k = blockIdx.x * 256 + threadIdx.x;   // 4 blocks x 256 = 1024 = K
    counts[k] = 0u;
    float v[DEMB];
#pragma unroll
    for (int d = 0; d < DEMB; ++d) v[d] = emb[k * DEMB + d];
    // ne: numpy pairwise-8 sum (unchanged from all passing rounds)
    float r[8];
#pragma unroll
    for (int j = 0; j < 8; ++j) r[j] = v[j] * v[j];
#pragma unroll
    for (int i = 8; i < 64; i += 8)
#pragma unroll
        for (int j = 0; j < 8; ++j) r[j] = r[j] + v[i + j] * v[i + j];
    ne[k] = ((r[0] + r[1]) + (r[2] + r[3])) + ((r[4] + r[5]) + (r[6] + r[7]));
    // bf16 pack: ebf[k][j] = (bf(v[2j+1])<<16) | bf(v[2j])
#pragma unroll
    for (int j = 0; j < 32; ++j)
        ebf[k * 32 + j] = f2bf1(v[2 * j]) | (f2bf1(v[2 * j + 1]) << 16);
    // emax
    float m = 0.0f;
#pragma unroll
    for (int d = 0; d < DEMB; ++d) m = fmaxf(m, fabsf(v[d]));
#pragma unroll
    for (int off = 32; off > 0; off >>= 1) m = fmaxf(m, __shfl_xor(m, off, 64));
    if ((threadIdx.x & 63) == 0) sm[threadIdx.x >> 6] = m;
    __syncthreads();
    if (threadIdx.x == 0)
        emax4[blockIdx.x] = fmaxf(fmaxf(sm[0], sm[1]), fmaxf(sm[2], sm[3]));
}

__global__ __launch_bounds__(256) void vq_main(const float* __restrict__ lat,
                                               const float* __restrict__ emb,
                                               const float* __restrict__ ne,
                                               const unsigned int* __restrict__ ebf,
                                               const float* __restrict__ emax4,
                                               float* __restrict__ outq,
                                               float* __restrict__ onehot,
                                               unsigned int* __restrict__ counts,
                                               float* __restrict__ partials) {
    __shared__ float xls[64 * XS];
    __shared__ float tauv[64], nxv[64];
    __shared__ unsigned int cnt[64];
    __shared__ int cand[64][16];
    __shared__ int ibrow[64];

    const int lane = threadIdx.x & 63;
    const int wq = __builtin_amdgcn_readfirstlane(threadIdx.x >> 6);
    const int n0 = blockIdx.x * 64;
    const int bimg = n0 >> 12;
    const int hw0 = n0 & 4095;

    // Stage x tile (wave wq loads d in [wq*16,+16) for all 64 rows).
    {
        const float* latp = lat + (size_t)bimg * (DEMB * 4096) + hw0 + lane;
#pragma unroll
        for (int dd = 0; dd < 16; ++dd) {
            int d = (wq << 4) + dd;
            xls[lane * XS + d] = latp[(size_t)d * 4096];
        }
    }
    if (threadIdx.x < 64) cnt[threadIdx.x] = 0u;
    __syncthreads();

    // Per-row nx (pairwise-8, contract off), Sx, tau. Thread tid = row.
    if (threadIdx.x < 64) {
#pragma clang fp contract(off)
        const float* xr = &xls[threadIdx.x * XS];
        float r[8];
#pragma unroll
        for (int j = 0; j < 8; ++j) { float v = xr[j]; r[j] = v * v; }
#pragma unroll
        for (int i = 8; i < 64; i += 8)
#pragma unroll
            for (int j = 0; j < 8; ++j) { float v = xr[i + j]; r[j] = r[j] + v * v; }
        float nx = ((r[0] + r[1]) + (r[2] + r[3])) + ((r[4] + r[5]) + (r[6] + r[7]));
        float Sx = 0.0f;
#pragma unroll
        for (int d = 0; d < DEMB; ++d) Sx += fabsf(xr[d]);
        float emax = fmaxf(fmaxf(emax4[0], emax4[1]), fmaxf(emax4[2], emax4[3])) * 1.01f;
        nxv[threadIdx.x] = nx;
        tauv[threadIdx.x] = Sx * emax * 0.017f + nx * 3e-7f + 2e-7f;
    }

    // A-frags for this wave's 16 rows: lane holds row (wq*16 + (lane&15)),
    // k = 32*ks + 8*(lane>>4) + i  (i=0..7), converted RN to bf16.
    const int g = lane >> 4;
    const int arow = (wq << 4) + (lane & 15);
    bf16x8 afr0, afr1;
    {
        const float* xp0 = &xls[arow * XS + 8 * g];
        const float* xp1 = &xls[arow * XS + 32 + 8 * g];
        AU a0, a1;
#pragma unroll
        for (int j = 0; j < 4; ++j) {
            a0.u[j] = f2bf1(xp0[2 * j]) | (f2bf1(xp0[2 * j + 1]) << 16);
            a1.u[j] = f2bf1(xp1[2 * j]) | (f2bf1(xp1[2 * j + 1]) << 16);
        }
        afr0 = a0.v; afr1 = a1.v;
    }
    __syncthreads();   // tauv/nxv visible

    // PASS A: stream all 64 code-tiles, track per-row min of
    // s = ne_k - 2*dot_bf16. Zero-fill one one_hot row per tile.
    float2* ohf2 = (float2*)onehot;
    const float2 z2 = make_float2(0.0f, 0.0f);
    float rmin0 = __builtin_inff(), rmin1 = __builtin_inff();
    float rmin2 = __builtin_inff(), rmin3 = __builtin_inff();
    for (int nt = 0; nt < 64; ++nt) {
        const int code = nt * 16 + (lane & 15);
        const bf16x8* bp = (const bf16x8*)(ebf + (size_t)code * 32 + g * 4);
        bf16x8 b0 = bp[0];
        bf16x8 b1 = bp[4];          // +64B = ks=1 chunk
        f32x4 c = {0.0f, 0.0f, 0.0f, 0.0f};
        c = __builtin_amdgcn_mfma_f32_16x16x32_bf16(afr0, b0, c, 0, 0, 0);
        c = __builtin_amdgcn_mfma_f32_16x16x32_bf16(afr1, b1, c, 0, 0, 0);
        float nek = ne[code];
        rmin0 = fminf(rmin0, __builtin_fmaf(-2.0f, c[0], nek));
        rmin1 = fminf(rmin1, __builtin_fmaf(-2.0f, c[1], nek));
        rmin2 = fminf(rmin2, __builtin_fmaf(-2.0f, c[2], nek));
        rmin3 = fminf(rmin3, __builtin_fmaf(-2.0f, c[3], nek));
        float2* zp = ohf2 + (((size_t)(n0 + nt)) << 9) + (wq << 7) + lane;
        zp[0] = z2;
        zp[64] = z2;
    }
    // cross-lane min over the 16 cols (lanes sharing g hold rows g*4+r)
#pragma unroll
    for (int m = 1; m < 16; m <<= 1) {
        rmin0 = fminf(rmin0, __shfl_xor(rmin0, m, 64));
        rmin1 = fminf(rmin1, __shfl_xor(rmin1, m, 64));
        rmin2 = fminf(rmin2, __shfl_xor(rmin2, m, 64));
        rmin3 = fminf(rmin3, __shfl_xor(rmin3, m, 64));
    }
    const int rowb = (wq << 4) + (g << 2);
    float TL0 = rmin0 + tauv[rowb + 0];
    float TL1 = rmin1 + tauv[rowb + 1];
    float TL2 = rmin2 + tauv[rowb + 2];
    float TL3 = rmin3 + tauv[rowb + 3];

    // PASS B: recompute (bit-identical), collect candidates s <= T.
    for (int nt = 0; nt < 64; ++nt) {
        const int code = nt * 16 + (lane & 15);
        const bf16x8* bp = (const bf16x8*)(ebf + (size_t)code * 32 + g * 4);
        bf16x8 b0 = bp[0];
        bf16x8 b1 = bp[4];
        f32x4 c = {0.0f, 0.0f, 0.0f, 0.0f};
        c = __builtin_amdgcn_mfma_f32_16x16x32_bf16(afr0, b0, c, 0, 0, 0);
        c = __builtin_amdgcn_mfma_f32_16x16x32_bf16(afr1, b1, c, 0, 0, 0);
        float nek = ne[code];
        float s0 = __builtin_fmaf(-2.0f, c[0], nek);
        float s1 = __builtin_fmaf(-2.0f, c[1], nek);
        float s2 = __builtin_fmaf(-2.0f, c[2], nek);
        float s3 = __builtin_fmaf(-2.0f, c[3], nek);
        if (s0 <= TL0) { unsigned p = atomicAdd(&cnt[rowb + 0], 1u); if (p < 16u) cand[rowb + 0][p] = code; }
        if (s1 <= TL1) { unsigned p = atomicAdd(&cnt[rowb + 1], 1u); if (p < 16u) cand[rowb + 1][p] = code; }
        if (s2 <= TL2) { unsigned p = atomicAdd(&cnt[rowb + 2], 1u); if (p < 16u) cand[rowb + 2][p] = code; }
        if (s3 <= TL3) { unsigned p = atomicAdd(&cnt[rowb + 3], 1u); if (p < 16u) cand[rowb + 3][p] = code; }
    }
    __syncthreads();   // drains vmcnt (zero-fill done) + cand lists visible

    // REFINE: lane<16 of each wave handles row = wq*16+lane.
    if (lane < 16) {
        const int row = (wq << 4) + lane;
        const unsigned c_ = cnt[row];
        int ib;
        if (c_ == 1u) {
            ib = cand[row][0];
        } else {
#pragma clang fp contract(off)
            const float* xr = &xls[row * XS];
            const float nx = nxv[row];
            float bd = __builtin_inff();
            int bk = 0x7FFFFFFF;
            if (c_ <= 16u) {
                for (unsigned j = 0; j < c_; ++j) {
                    int k = cand[row][j];
                    const float* er = emb + (size_t)k * DEMB;
                    float acc = 0.0f;
                    for (int d = 0; d < DEMB; ++d) acc = __builtin_fmaf(xr[d], er[d], acc);
                    float A_ = nx + ne[k];
                    float dist = A_ - 2.0f * acc;
                    if (dist < bd || (dist == bd && k < bk)) { bd = dist; bk = k; }
                }
            } else {   // overflow fallback: exact full scan (correct, ~never)
                for (int k = 0; k < KEMB; ++k) {
                    const float* er = emb + (size_t)k * DEMB;
                    float acc = 0.0f;
                    for (int d = 0; d < DEMB; ++d) acc = __builtin_fmaf(xr[d], er[d], acc);
                    float A_ = nx + ne[k];
                    float dist = A_ - 2.0f * acc;
                    if (dist < bd) { bd = dist; bk = k; }
                }
            }
            ib = bk;
        }
        ibrow[row] = ib;
        onehot[(size_t)(n0 + row) * KEMB + ib] = 1.0f;
        atomicAdd(&counts[ib], 1u);
    }
    __syncthreads();

    // Epilogue: out = lat + (q - lat), loss partial. Wave wq: d [wq*16,+16).
    const int ib = ibrow[lane];
    const float* xl = &xls[lane * XS];
    float lsum = 0.0f;
    const size_t obase = (size_t)bimg * (DEMB * 4096) + hw0 + lane;
    {
#pragma clang fp contract(off)
        const float4* eq4 = (const float4*)(emb + (size_t)ib * DEMB + (wq << 4));
#pragma unroll
        for (int c4 = 0; c4 < 4; ++c4) {
            float4 qv = eq4[c4];
            int dbase = (wq << 4) + 4 * c4;
            float xv0 = xl[dbase + 0];
            float xv1 = xl[dbase + 1];
            float xv2 = xl[dbase + 2];
            float xv3 = xl[dbase + 3];
            float f0 = qv.x - xv0, f1 = qv.y - xv1;
            float f2 = qv.z - xv2, f3 = qv.w - xv3;
            outq[obase + (size_t)(dbase + 0) * 4096] = xv0 + f0;
            outq[obase + (size_t)(dbase + 1) * 4096] = xv1 + f1;
            outq[obase + (size_t)(dbase + 2) * 4096] = xv2 + f2;
            outq[obase + (size_t)(dbase + 3) * 4096] = xv3 + f3;
            lsum = lsum + f0 * f0;
            lsum = lsum + f1 * f1;
            lsum = lsum + f2 * f2;
            lsum = lsum + f3 * f3;
        }
    }
#pragma unroll
    for (int off = 32; off > 0; off >>= 1) lsum += __shfl_xor(lsum, off, 64);
    if (lane == 0) partials[blockIdx.x * 4 + wq] = lsum;
}

__global__ __launch_bounds__(1024) void vq_final(const unsigned int* __restrict__ counts,
                                                 const float* __restrict__ partials,
                                                 float* __restrict__ out01) {
    __shared__ float sb[1024];
    int t = threadIdx.x;
    float s = 0.0f;
#pragma unroll
    for (int i = 0; i < 8; ++i) s += partials[t + 1024 * i];
    sb[t] = s;
    __syncthreads();
    for (int off = 512; off > 0; off >>= 1) {
        if (t < off) sb[t] = sb[t] + sb[t + off];
        __syncthreads();
    }
    if (t == 0) {
        float m = sb[0] / 8388608.0f;
        out01[0] = m * 0.25f + m;
    }
    __syncthreads();
    float p = (float)counts[t] * (1.0f / 131072.0f);
    sb[t] = p * logf(p + 1e-10f);
    __syncthreads();
    for (int off = 512; off > 0; off >>= 1) {
        if (t < off) sb[t] = sb[t] + sb[t + off];
        __syncthreads();
    }
    if (t == 0) out01[1] = expf(-sb[0]);
}

extern "C" void kernel_launch(void* const* d_in, const int* in_sizes, int n_in,
                              void* d_out, int out_size, void* d_ws, size_t ws_size,
                              hipStream_t stream) {
    const float* lat = (const float*)d_in[0];
    const float* emb = (const float*)d_in[1];
    float* out = (float*)d_out;
    float* ws = (float*)d_ws;

    float* ne = ws;                                            // [1024]
    unsigned int* ebf = (unsigned int*)(ws + 1024);            // [32768]
    float* emax4 = ws + 1024 + 32768;                          // [4]
    unsigned int* counts = (unsigned int*)(ws + 1024 + 32768 + 4);  // [1024]
    float* partials = ws + 1024 + 32768 + 4 + 1024;            // [8192]

    float* outq = out + 2;
    float* onehot = out + 2 + 8388608;

    vq_prep<<<4, 256, 0, stream>>>(emb, ne, ebf, counts, emax4);
    vq_main<<<2048, 256, 0, stream>>>(lat, emb, ne, ebf, emax4, outq, onehot,
                                      counts, partials);
    vq_final<<<1, 1024, 0, stream>>>(counts, partials, out);
}